// Round 1
// baseline (259.459 us; speedup 1.0000x reference)
//
#include <hip/hip_runtime.h>

#ifndef __has_builtin
#define __has_builtin(x) 0
#endif

__device__ __forceinline__ float fast_exp2(float v) {
#if __has_builtin(__builtin_amdgcn_exp2f)
    return __builtin_amdgcn_exp2f(v);   // v_exp_f32 (exp2), ~1 ulp
#else
    return exp2f(v);
#endif
}

constexpr int R = 20;   // reads per site
constexpr int C = 32;   // channels
constexpr int B = 32;   // bins

// One thread per (site, channel). lane = channel -> 128B-contiguous access per site.
// KDE via recurrence: exp(-50(x - b/31)^2) = w_b, w_{b+1} = w_b * m_b, m_{b+1} = m_b * q
//   w_0 = exp2(-K x^2), m_0 = exp2(A2*x + B0), q = exp2(2*B0)
//   K = 50*log2(e), A2 = 2K/31, B0 = -K/961
__global__ __launch_bounds__(256) void kde_kernel(const float* __restrict__ x,
                                                  float* __restrict__ out,
                                                  int nsites) {
    int t = blockIdx.x * blockDim.x + threadIdx.x;
    int c = t & (C - 1);
    int n = t >> 5;
    if (n >= nsites) return;

    const float K  = 72.13475204444817f;      // 50 * log2(e)
    const float A2 = 4.6538549706095594f;     // 2K/31
    const float B0 = -0.07506217694531545f;   // -K/961
    const float q  = fast_exp2(2.0f * B0);    // exp2(-2K/961)

    float acc[B];
#pragma unroll
    for (int b = 0; b < B; ++b) acc[b] = 0.0f;

    const float* xp = x + (size_t)n * (R * C) + c;

#pragma unroll 4
    for (int r = 0; r < R; ++r) {
        float xv = xp[(size_t)r * C];
        float w = fast_exp2(-K * xv * xv);            // exp(-50 x^2)
        float m = fast_exp2(fmaf(xv, A2, B0));        // step multiplier
#pragma unroll
        for (int b = 0; b < B; ++b) {
            acc[b] += w;   // w == exp(-50 (x - b/31)^2)
            w *= m;
            m *= q;
        }
    }

    // coef / R = (1/sqrt(2*pi*0.01)) / 20
    const float scale = 0.19947114020071635f;
    float* op = out + (size_t)n * (B * C) + c;
#pragma unroll
    for (int b = 0; b < B; ++b) op[(size_t)b * C] = acc[b] * scale;
}

extern "C" void kernel_launch(void* const* d_in, const int* in_sizes, int n_in,
                              void* d_out, int out_size, void* d_ws, size_t ws_size,
                              hipStream_t stream) {
    const float* x = (const float*)d_in[0];
    float* out = (float*)d_out;
    int nsites = in_sizes[0] / (R * C);          // 131072
    int total = nsites * C;                      // one thread per (site, channel)
    int block = 256;
    int grid = (total + block - 1) / block;
    hipLaunchKernelGGL(kde_kernel, dim3(grid), dim3(block), 0, stream, x, out, nsites);
}

// Round 2
// 210.858 us; speedup vs baseline: 1.2305x; 1.2305x over previous
//
#include <hip/hip_runtime.h>

#ifndef __has_builtin
#define __has_builtin(x) 0
#endif

__device__ __forceinline__ float fast_exp2(float v) {
#if __has_builtin(__builtin_amdgcn_exp2f)
    return __builtin_amdgcn_exp2f(v);   // v_exp_f32 (base-2), ~1 ulp
#else
    return exp2f(v);
#endif
}

constexpr int R = 20;   // reads per site
constexpr int C = 32;   // channels
constexpr int B = 32;   // bins

// One thread per (site, channel); lane = channel -> every load/store instr is
// 128B-contiguous per site (2 sites per wave64).
//
// KDE recurrence: exp(-50(x - b/31)^2) = w_b with
//   w_0 = exp2(-K x^2), w_{b+1} = w_b * m_b, m_{b+1} = m_b * q
//   m_0 = exp2(A2*x + B0), K = 50*log2(e), A2 = 2K/31, B0 = -K/961, q = 2^(2*B0)
//
// All 20 reads are prefetched into registers up front so the 20 global loads
// are in flight before the ~4300-cycle compute burst begins (per-wave
// decoupling; progressive vmcnt waits consume them in order).
__global__ __launch_bounds__(256, 6) void kde_kernel(const float* __restrict__ x,
                                                     float* __restrict__ out,
                                                     int nsites) {
    int t = blockIdx.x * blockDim.x + threadIdx.x;
    int c = t & (C - 1);
    int n = t >> 5;
    if (n >= nsites) return;

    const float K  = 72.13475204444817f;   // 50 * log2(e)
    const float A2 = 4.6538549706095594f;  // 2K/31
    const float B0 = -0.07506217694531545f;// -K/961
    const float q  = 0.9011728f;           // 2^(2*B0), hard-coded literal

    const float* xp = x + (size_t)n * (R * C) + c;

    // prefetch: all 20 loads issued before any compute
    float xv[R];
#pragma unroll
    for (int r = 0; r < R; ++r) xv[r] = xp[(size_t)r * C];

    float acc[B];
#pragma unroll
    for (int b = 0; b < B; ++b) acc[b] = 0.0f;

#pragma unroll
    for (int r = 0; r < R; ++r) {
        float v = xv[r];
        float u = v * v;
        float w = fast_exp2(u * -K);            // exp(-50 x^2)
        float m = fast_exp2(fmaf(v, A2, B0));   // step multiplier
#pragma unroll
        for (int b = 0; b < B; ++b) {
            acc[b] += w;   // w == exp(-50 (x - b/31)^2)
            w *= m;
            m *= q;
        }
    }

    // coef / R = (1/sqrt(2*pi*0.01)) / 20
    const float scale = 0.19947114020071635f;
    float* op = out + (size_t)n * (B * C) + c;
#pragma unroll
    for (int b = 0; b < B; ++b) op[(size_t)b * C] = acc[b] * scale;
}

extern "C" void kernel_launch(void* const* d_in, const int* in_sizes, int n_in,
                              void* d_out, int out_size, void* d_ws, size_t ws_size,
                              hipStream_t stream) {
    const float* x = (const float*)d_in[0];
    float* out = (float*)d_out;
    int nsites = in_sizes[0] / (R * C);          // 131072
    int total = nsites * C;                      // one thread per (site, channel)
    int block = 256;
    int grid = (total + block - 1) / block;
    hipLaunchKernelGGL(kde_kernel, dim3(grid), dim3(block), 0, stream, x, out, nsites);
}

// Round 3
// 170.481 us; speedup vs baseline: 1.5219x; 1.2368x over previous
//
#include <hip/hip_runtime.h>
#include <math.h>

#ifndef __has_builtin
#define __has_builtin(x) 0
#endif

__device__ __forceinline__ float fast_exp2(float v) {
#if __has_builtin(__builtin_amdgcn_exp2f)
    return __builtin_amdgcn_exp2f(v);   // v_exp_f32 (base-2), ~1 ulp
#else
    return exp2f(v);
#endif
}

constexpr int R = 20;   // reads per site
constexpr int C = 32;   // channels
constexpr int B = 32;   // bins

// One thread per (site, channel); lane = channel -> every load/store instr is
// two 128B-contiguous segments per wave64 (2 sites). Fully coalesced.
//
// KDE factorization (bin centers b/31, sigma^2=0.01):
//   exp(-50(x - b/31)^2) = 2^{-Kx^2} * (2^{A2*x + B0})^b * 2^{-(K/961) b(b-1)}
//   with K = 50*log2(e), A2 = 2K/31, B0 = -K/961.
// The last factor is DATA-INDEPENDENT -> hoisted into the per-bin epilogue
// constant, fused with log2(coef/R). Inner loop is 2 VALU ops per bin:
//   acc[b] += P;  P *= m0       (P_0 = w0 = 2^{-Kx^2})
__global__ __launch_bounds__(256, 6) void kde_kernel(const float* __restrict__ x,
                                                     float* __restrict__ out,
                                                     int nsites) {
    int t = blockIdx.x * blockDim.x + threadIdx.x;
    int c = t & (C - 1);
    int n = t >> 5;
    if (n >= nsites) return;

    const float K  = 72.13475204444817f;    // 50 * log2(e)
    const float A2 = 4.6538549706095594f;   // 2K/31
    const float B0 = -0.07506217694531545f; // -K/961

    const float* xp = x + (size_t)n * (R * C) + c;

    // prefetch: all 20 loads in flight before compute
    float xv[R];
#pragma unroll
    for (int r = 0; r < R; ++r) xv[r] = xp[(size_t)r * C];

    float acc[B];
#pragma unroll
    for (int b = 0; b < B; ++b) acc[b] = 0.0f;

#pragma unroll
    for (int r = 0; r < R; ++r) {
        float v = xv[r];
        float P  = fast_exp2(v * v * -K);          // w0 = exp(-50 x^2)
        float m0 = fast_exp2(fmaf(v, A2, B0));     // per-bin step multiplier
#pragma unroll
        for (int b = 0; b < B; ++b) {
            acc[b] += P;       // P == w0 * m0^b
            P *= m0;
        }
    }

    // epilogue: out[b] = acc[b] * 2^{-(K/961) b(b-1)} * (coef/R)
    // log2(coef/R) = log2(0.19947114020071635) = -2.3257480449
    float* op = out + (size_t)n * (B * C) + c;
#pragma unroll
    for (int b = 0; b < B; ++b) {
        const float g = (float)(-0.07506217694531545 * (double)(b * (b - 1))
                                - 2.3257480449);   // compile-time constant
        op[(size_t)b * C] = acc[b] * exp2f(g);     // exp2f(const) folds
    }
}

extern "C" void kernel_launch(void* const* d_in, const int* in_sizes, int n_in,
                              void* d_out, int out_size, void* d_ws, size_t ws_size,
                              hipStream_t stream) {
    const float* x = (const float*)d_in[0];
    float* out = (float*)d_out;
    int nsites = in_sizes[0] / (R * C);          // 131072
    int total = nsites * C;                      // one thread per (site, channel)
    int block = 256;
    int grid = (total + block - 1) / block;
    hipLaunchKernelGGL(kde_kernel, dim3(grid), dim3(block), 0, stream, x, out, nsites);
}